// Round 1
// baseline (3940.479 us; speedup 1.0000x reference)
//
#include <hip/hip_runtime.h>
#include <cstdint>
#include <cstddef>

#define NY 8400
#define NR 300
#define NF 8700
#define MAX_CHUNKS 136   // ceil(8700/64)
#define STHR 0.5f
#define ITHR 0.5f

// IOU with explicit-rounding ops so fp-contraction cannot perturb the
// iou > 0.5 comparison vs the numpy fp32 reference.
__device__ __forceinline__ float iou_pair(float4 a, float4 b) {
    float ltx = fmaxf(a.x, b.x);
    float lty = fmaxf(a.y, b.y);
    float rbx = fminf(a.z, b.z);
    float rby = fminf(a.w, b.w);
    float w = fmaxf(__fsub_rn(rbx, ltx), 0.0f);
    float h = fmaxf(__fsub_rn(rby, lty), 0.0f);
    float inter  = __fmul_rn(w, h);
    float area_a = __fmul_rn(__fsub_rn(a.z, a.x), __fsub_rn(a.w, a.y));
    float area_b = __fmul_rn(__fsub_rn(b.z, b.x), __fsub_rn(b.w, b.y));
    float denom  = __fsub_rn(__fadd_rn(area_a, area_b), inter);
    float d = denom > 0.0f ? denom : 1.0f;
    return __fdiv_rn(inter, d);
}

// yolo_raw: (5, 8400) channel-major -> xyxy (N,4), conf (N)
__global__ void prep_yolo(const float* __restrict__ y,
                          float* __restrict__ xyxy, float* __restrict__ conf, int N) {
    int i = blockIdx.x * blockDim.x + threadIdx.x;
    if (i >= N) return;
    float cx = y[0 * N + i], cy = y[1 * N + i];
    float w  = y[2 * N + i], h  = y[3 * N + i];
    float c  = y[4 * N + i];
    xyxy[i * 4 + 0] = cx - w * 0.5f;
    xyxy[i * 4 + 1] = cy - h * 0.5f;
    xyxy[i * 4 + 2] = cx + w * 0.5f;
    xyxy[i * 4 + 3] = cy + h * 0.5f;
    conf[i] = c;
}

// rtdetr_raw: (300,5) row-major. Single block: max-reduce conf then prep.
__global__ void prep_rtdetr(const float* __restrict__ r,
                            float* __restrict__ xyxy, float* __restrict__ conf, int N) {
    __shared__ float red[512];
    int t = threadIdx.x;
    float m = -INFINITY;
    for (int i = t; i < N; i += blockDim.x) m = fmaxf(m, r[i * 5 + 4]);
    red[t] = m;
    __syncthreads();
    for (int s = 256; s > 0; s >>= 1) {
        if (t < s) red[t] = fmaxf(red[t], red[t + s]);
        __syncthreads();
    }
    float mx = red[0];
    for (int i = t; i < N; i += blockDim.x) {
        float cx = r[i * 5 + 0], cy = r[i * 5 + 1];
        float w  = r[i * 5 + 2], h  = r[i * 5 + 3];
        float c  = r[i * 5 + 4];
        xyxy[i * 4 + 0] = cx - w * 0.5f;
        xyxy[i * 4 + 1] = cy - h * 0.5f;
        xyxy[i * 4 + 2] = cx + w * 0.5f;
        xyxy[i * 4 + 3] = cy + h * 0.5f;
        conf[i] = __fdiv_rn(c, mx);
    }
}

// Stable-descending rank sort: rank[i] = #{j: key_j > key_i} + #{j<i: key_j == key_i}
// Exactly reproduces jnp.argsort(-key) (stable) semantics. Scatter to sorted arrays.
__global__ void sort_by_conf(const float* __restrict__ xyxy, const float* __restrict__ conf,
                             float* __restrict__ xyxy_s, float* __restrict__ conf_s, int N) {
    int i = blockIdx.x * blockDim.x + threadIdx.x;
    if (i >= N) return;
    float ci = conf[i];
    float ki = (ci >= STHR) ? ci : -1.0f;
    int rank = 0;
    for (int j = 0; j < N; ++j) {
        float cj = conf[j];
        float kj = (cj >= STHR) ? cj : -1.0f;
        rank += (kj > ki) || (kj == ki && j < i);
    }
    xyxy_s[rank * 4 + 0] = xyxy[i * 4 + 0];
    xyxy_s[rank * 4 + 1] = xyxy[i * 4 + 1];
    xyxy_s[rank * 4 + 2] = xyxy[i * 4 + 2];
    xyxy_s[rank * 4 + 3] = xyxy[i * 4 + 3];
    conf_s[rank] = ci;
}

// One wave per (row i, 64-col chunk c): mask bit j = (j>i) && iou>thr.
// Chunks c < i/64 are never read by the scan -> skipped.
__global__ void nms_mask(const float* __restrict__ xyxy_s, uint64_t* __restrict__ mask,
                         int N, int nchunks) {
    int wid  = (blockIdx.x * blockDim.x + threadIdx.x) >> 6;
    int lane = threadIdx.x & 63;
    if (wid >= N * nchunks) return;
    int i = wid / nchunks;
    int c = wid - i * nchunks;
    if (c < (i >> 6)) return;          // never read
    int j = c * 64 + lane;
    float4 bi = *(const float4*)(xyxy_s + i * 4);
    bool bit = false;
    if (j < N && j > i) {
        float4 bj = *(const float4*)(xyxy_s + j * 4);
        bit = iou_pair(bi, bj) > ITHR;
    }
    uint64_t m = __ballot(bit);
    if (lane == 0) mask[(size_t)i * nchunks + c] = m;
}

// Single-block sequential suppression scan over the valid (sorted) prefix.
__global__ void nms_scan(const float* __restrict__ conf_s,
                         const uint64_t* __restrict__ mask,
                         uint64_t* __restrict__ removed_out,
                         int N, int nchunks) {
    __shared__ uint64_t removed[MAX_CHUNKS];
    __shared__ int red[256];
    int t = threadIdx.x;

    // count valid (conf >= thr); sorted order puts them in the prefix
    int cnt = 0;
    for (int j = t; j < N; j += blockDim.x) cnt += (conf_s[j] >= STHR) ? 1 : 0;
    red[t] = cnt;
    __syncthreads();
    for (int s = 128; s > 0; s >>= 1) {
        if (t < s) red[t] += red[t + s];
        __syncthreads();
    }
    int nvalid = red[0];

    // init removed: bits j >= nvalid pre-suppressed
    for (int c = t; c < nchunks; c += blockDim.x) {
        int base = c * 64;
        uint64_t m = 0;
        if (base >= nvalid) m = ~0ull;
        else if (base + 64 > nvalid) m = (~0ull) << (nvalid - base);
        removed[c] = m;
    }
    __syncthreads();

    // sequential: writes at iteration i only set bits > i, so the bit-i read
    // is race-free with a single trailing barrier.
    for (int i = 0; i < nvalid; ++i) {
        bool sup = (removed[i >> 6] >> (i & 63)) & 1ull;
        if (!sup) {
            const uint64_t* row = mask + (size_t)i * nchunks;
            for (int c = t; c < nchunks; c += blockDim.x)
                if (c >= (i >> 6)) removed[c] |= row[c];
        }
        __syncthreads();
    }
    for (int c = t; c < nchunks; c += blockDim.x) removed_out[c] = removed[c];
}

// out[j] = keep ? [box, score] : 0
__global__ void write_bs(const float* __restrict__ xyxy_s, const float* __restrict__ conf_s,
                         const uint64_t* __restrict__ removed,
                         float* __restrict__ out, int N) {
    int j = blockIdx.x * blockDim.x + threadIdx.x;
    if (j >= N) return;
    bool keep = !((removed[j >> 6] >> (j & 63)) & 1ull);
    float4 b = *(const float4*)(xyxy_s + j * 4);
    out[j * 5 + 0] = keep ? b.x : 0.0f;
    out[j * 5 + 1] = keep ? b.y : 0.0f;
    out[j * 5 + 2] = keep ? b.z : 0.0f;
    out[j * 5 + 3] = keep ? b.w : 0.0f;
    out[j * 5 + 4] = keep ? conf_s[j] : 0.0f;
}

// concat y_bs[:, :4] + r_bs[:, :4] -> xyxy; col 4 -> conf
__global__ void concat_final(const float* __restrict__ y_bs, const float* __restrict__ r_bs,
                             float* __restrict__ xyxy, float* __restrict__ conf,
                             int Ny, int Nr) {
    int i = blockIdx.x * blockDim.x + threadIdx.x;
    if (i >= Ny + Nr) return;
    const float* src = (i < Ny) ? (y_bs + (size_t)i * 5) : (r_bs + (size_t)(i - Ny) * 5);
    xyxy[i * 4 + 0] = src[0];
    xyxy[i * 4 + 1] = src[1];
    xyxy[i * 4 + 2] = src[2];
    xyxy[i * 4 + 3] = src[3];
    conf[i] = src[4];
}

static void run_nms_stage(const float* xyxy_in, const float* conf_in,
                          float* xyxy_s, float* conf_s,
                          uint64_t* removed, uint64_t* mask,
                          float* out_bs, int N, hipStream_t stream) {
    int nch = (N + 63) / 64;
    sort_by_conf<<<(N + 255) / 256, 256, 0, stream>>>(xyxy_in, conf_in, xyxy_s, conf_s, N);
    int waves = N * nch;
    nms_mask<<<(waves + 3) / 4, 256, 0, stream>>>(xyxy_s, mask, N, nch);
    nms_scan<<<1, 256, 0, stream>>>(conf_s, mask, removed, N, nch);
    write_bs<<<(N + 255) / 256, 256, 0, stream>>>(xyxy_s, conf_s, removed, out_bs, N);
}

extern "C" void kernel_launch(void* const* d_in, const int* in_sizes, int n_in,
                              void* d_out, int out_size, void* d_ws, size_t ws_size,
                              hipStream_t stream) {
    const float* yolo   = (const float*)d_in[0];  // (1,5,8400)
    const float* rtdetr = (const float*)d_in[1];  // (1,300,5)
    float* out = (float*)d_out;                   // (8700,5)
    float* ws  = (float*)d_ws;

    // ws layout (floats)
    float* xyxy_in = ws;                 // 8700*4 = 34800
    float* conf_in = ws + 34800;         // 8700
    float* xyxy_s  = ws + 43500;         // 34800 (16B-aligned: 43500*4 % 16 == 0)
    float* conf_s  = ws + 78300;         // 8700
    float* y_bs    = ws + 87000;         // 8400*5 = 42000
    float* r_bs    = ws + 129000;        // 300*5  = 1500
    uint64_t* removed = (uint64_t*)((char*)d_ws + 522000);           // 136 u64
    uint64_t* mask    = (uint64_t*)((char*)d_ws + 523088);           // 8700*136 u64 (~9.5MB)

    // Stage 1: YOLO
    prep_yolo<<<(NY + 255) / 256, 256, 0, stream>>>(yolo, xyxy_in, conf_in, NY);
    run_nms_stage(xyxy_in, conf_in, xyxy_s, conf_s, removed, mask, y_bs, NY, stream);

    // Stage 2: RT-DETR
    prep_rtdetr<<<1, 512, 0, stream>>>(rtdetr, xyxy_in, conf_in, NR);
    run_nms_stage(xyxy_in, conf_in, xyxy_s, conf_s, removed, mask, r_bs, NR, stream);

    // Stage 3: final over concat
    concat_final<<<(NF + 255) / 256, 256, 0, stream>>>(y_bs, r_bs, xyxy_in, conf_in, NY, NR);
    run_nms_stage(xyxy_in, conf_in, xyxy_s, conf_s, removed, mask, out, NF, stream);
}

// Round 2
// 2237.824 us; speedup vs baseline: 1.7609x; 1.7609x over previous
//
#include <hip/hip_runtime.h>
#include <cstdint>
#include <cstddef>

#define NY 8400
#define NR 300
#define NF 8700
#define STHR 0.5f
#define ITHR 0.5f
#define BATCH 8

// IOU with explicit-rounding ops so fp-contraction cannot perturb the
// iou > 0.5 comparison vs the numpy fp32 reference.
__device__ __forceinline__ float iou_pair(float4 a, float4 b) {
    float ltx = fmaxf(a.x, b.x);
    float lty = fmaxf(a.y, b.y);
    float rbx = fminf(a.z, b.z);
    float rby = fminf(a.w, b.w);
    float w = fmaxf(__fsub_rn(rbx, ltx), 0.0f);
    float h = fmaxf(__fsub_rn(rby, lty), 0.0f);
    float inter  = __fmul_rn(w, h);
    float area_a = __fmul_rn(__fsub_rn(a.z, a.x), __fsub_rn(a.w, a.y));
    float area_b = __fmul_rn(__fsub_rn(b.z, b.x), __fsub_rn(b.w, b.y));
    float denom  = __fsub_rn(__fadd_rn(area_a, area_b), inter);
    float d = denom > 0.0f ? denom : 1.0f;
    return __fdiv_rn(inter, d);
}

// yolo_raw: (5, 8400) channel-major -> xyxy (N,4), conf (N)
__global__ void prep_yolo(const float* __restrict__ y,
                          float* __restrict__ xyxy, float* __restrict__ conf, int N) {
    int i = blockIdx.x * blockDim.x + threadIdx.x;
    if (i >= N) return;
    float cx = y[0 * N + i], cy = y[1 * N + i];
    float w  = y[2 * N + i], h  = y[3 * N + i];
    float c  = y[4 * N + i];
    xyxy[i * 4 + 0] = cx - w * 0.5f;
    xyxy[i * 4 + 1] = cy - h * 0.5f;
    xyxy[i * 4 + 2] = cx + w * 0.5f;
    xyxy[i * 4 + 3] = cy + h * 0.5f;
    conf[i] = c;
}

// rtdetr_raw: (300,5) row-major. Single block: max-reduce conf then prep.
__global__ void prep_rtdetr(const float* __restrict__ r,
                            float* __restrict__ xyxy, float* __restrict__ conf, int N) {
    __shared__ float red[512];
    int t = threadIdx.x;
    float m = -INFINITY;
    for (int i = t; i < N; i += blockDim.x) m = fmaxf(m, r[i * 5 + 4]);
    red[t] = m;
    __syncthreads();
    for (int s = 256; s > 0; s >>= 1) {
        if (t < s) red[t] = fmaxf(red[t], red[t + s]);
        __syncthreads();
    }
    float mx = red[0];
    for (int i = t; i < N; i += blockDim.x) {
        float cx = r[i * 5 + 0], cy = r[i * 5 + 1];
        float w  = r[i * 5 + 2], h  = r[i * 5 + 3];
        float c  = r[i * 5 + 4];
        xyxy[i * 4 + 0] = cx - w * 0.5f;
        xyxy[i * 4 + 1] = cy - h * 0.5f;
        xyxy[i * 4 + 2] = cx + w * 0.5f;
        xyxy[i * 4 + 3] = cy + h * 0.5f;
        conf[i] = __fdiv_rn(c, mx);
    }
}

// Stable-descending rank sort: rank[i] = #{j: key_j > key_i} + #{j<i: key_j == key_i}
// Exactly reproduces jnp.argsort(-key) (stable) semantics. Scatter to sorted arrays.
__global__ void sort_by_conf(const float* __restrict__ xyxy, const float* __restrict__ conf,
                             float* __restrict__ xyxy_s, float* __restrict__ conf_s, int N) {
    int i = blockIdx.x * blockDim.x + threadIdx.x;
    if (i >= N) return;
    float ci = conf[i];
    float ki = (ci >= STHR) ? ci : -1.0f;
    int rank = 0;
    for (int j = 0; j < N; ++j) {
        float cj = conf[j];
        float kj = (cj >= STHR) ? cj : -1.0f;
        rank += (kj > ki) || (kj == ki && j < i);
    }
    xyxy_s[rank * 4 + 0] = xyxy[i * 4 + 0];
    xyxy_s[rank * 4 + 1] = xyxy[i * 4 + 1];
    xyxy_s[rank * 4 + 2] = xyxy[i * 4 + 2];
    xyxy_s[rank * 4 + 3] = xyxy[i * 4 + 3];
    conf_s[rank] = ci;
}

// One 256-thread block per row i; 4 waves stride the upper-triangle chunks.
__global__ void nms_mask_row(const float* __restrict__ xyxy_s, uint64_t* __restrict__ mask,
                             int N, int nchunks) {
    int i = blockIdx.x;
    int lane = threadIdx.x & 63;
    int wv   = threadIdx.x >> 6;   // 0..3
    float4 bi = *(const float4*)(xyxy_s + (size_t)i * 4);
    for (int c = (i >> 6) + wv; c < nchunks; c += 4) {
        int j = (c << 6) + lane;
        bool bit = false;
        if (j < N && j > i) {
            float4 bj = *(const float4*)(xyxy_s + (size_t)j * 4);
            bit = iou_pair(bi, bj) > ITHR;
        }
        uint64_t m = __ballot(bit);
        if (lane == 0) mask[(size_t)i * nchunks + c] = m;
    }
}

__device__ __forceinline__ uint64_t shfl64(uint64_t v, int src) {
    int lo = __shfl((int)(uint32_t)(v & 0xffffffffull), src, 64);
    int hi = __shfl((int)(uint32_t)(v >> 32), src, 64);
    return ((uint64_t)(uint32_t)hi << 32) | (uint32_t)lo;
}

// Single-wave batched word-skipping suppression scan.
// `removed` bitmap lives in registers: chunk cc owned by lane (cc&63), slot (cc>>6).
// Per 64-bit word of candidates: pull up to BATCH lowest unsuppressed bits, load all
// their mask rows in one latency window, resolve exact greedy order among them in
// registers, OR kept rows into the bitmap. Zero barriers, zero LDS.
__global__ void nms_scan_wave(const float* __restrict__ conf_s,
                              const uint64_t* __restrict__ mask,
                              uint64_t* __restrict__ removed_out,
                              int N, int nchunks) {
    int lane = threadIdx.x;  // 64 threads, 1 wave

    // nvalid = #{conf >= thr}; valid boxes occupy the sorted prefix
    int cnt = 0;
    for (int j = lane; j < N; j += 64) cnt += (conf_s[j] >= STHR) ? 1 : 0;
    #pragma unroll
    for (int s = 32; s > 0; s >>= 1) cnt += __shfl_down(cnt, s, 64);
    int nvalid = __shfl(cnt, 0, 64);

    // init removed: bits >= nvalid pre-suppressed
    uint64_t rem0, rem1, rem2;
    {
        int cc0 = lane, cc1 = 64 + lane, cc2 = 128 + lane;
        auto initc = [&](int cc) -> uint64_t {
            if (cc >= nchunks) return ~0ull;
            int base = cc << 6;
            if (base >= nvalid) return ~0ull;
            if (base + 64 > nvalid) return (~0ull) << (nvalid - base);
            return 0ull;
        };
        rem0 = initc(cc0); rem1 = initc(cc1); rem2 = initc(cc2);
    }

    int vchunks = (nvalid + 63) >> 6;
    for (int c = 0; c < vchunks; ++c) {
        int owner = c & 63, slot = c >> 6;
        uint64_t ownval = (slot == 0) ? rem0 : (slot == 1) ? rem1 : rem2;
        uint64_t w = ~shfl64(ownval, owner);   // unsuppressed candidates in chunk c
        uint64_t keptw = 0;

        while (w) {
            // extract up to BATCH lowest candidate bits (uniform)
            int p[BATCH]; int np = 0;
            uint64_t wt = w;
            #pragma unroll
            for (int k = 0; k < BATCH; ++k) {
                p[k] = 0;
                if (wt) { p[k] = (int)__builtin_ctzll(wt); wt &= wt - 1; np = k + 1; }
            }
            // issue all row loads (independent -> one latency window)
            uint64_t r[BATCH][3]; uint64_t rc[BATCH];
            #pragma unroll
            for (int k = 0; k < BATCH; ++k) {
                bool act = k < np;
                const uint64_t* base = mask + (size_t)((c << 6) + p[k]) * nchunks;
                rc[k] = act ? base[c] : 0ull;   // same-addr across lanes (broadcast)
                #pragma unroll
                for (int u = 0; u < 3; ++u) {
                    int cc = (u << 6) + lane;
                    bool ld = act && cc > c && cc < nchunks;
                    r[k][u] = ld ? base[cc] : 0ull;
                }
            }
            // exact greedy resolve within the batch:
            // p[k] kept iff no earlier-kept batch member suppresses it.
            uint64_t acc = 0, pm = 0;
            #pragma unroll
            for (int k = 0; k < BATCH; ++k) {
                if (k < np) {
                    uint64_t bit = 1ull << p[k];
                    pm |= bit;
                    if (!(acc & bit)) {
                        keptw |= bit;
                        acc   |= rc[k];
                        rem0 |= r[k][0]; rem1 |= r[k][1]; rem2 |= r[k][2];
                    }
                }
            }
            w &= ~pm;
            w &= ~acc;
        }
        // finalize chunk c: everything not kept is suppressed (or invalid tail)
        if (lane == owner) {
            uint64_t v = ~keptw;
            if (slot == 0) rem0 = v; else if (slot == 1) rem1 = v; else rem2 = v;
        }
    }

    if (lane < nchunks)       removed_out[lane]       = rem0;
    if (64 + lane < nchunks)  removed_out[64 + lane]  = rem1;
    if (128 + lane < nchunks) removed_out[128 + lane] = rem2;
}

// out[j] = keep ? [box, score] : 0
__global__ void write_bs(const float* __restrict__ xyxy_s, const float* __restrict__ conf_s,
                         const uint64_t* __restrict__ removed,
                         float* __restrict__ out, int N) {
    int j = blockIdx.x * blockDim.x + threadIdx.x;
    if (j >= N) return;
    bool keep = !((removed[j >> 6] >> (j & 63)) & 1ull);
    float4 b = *(const float4*)(xyxy_s + j * 4);
    out[j * 5 + 0] = keep ? b.x : 0.0f;
    out[j * 5 + 1] = keep ? b.y : 0.0f;
    out[j * 5 + 2] = keep ? b.z : 0.0f;
    out[j * 5 + 3] = keep ? b.w : 0.0f;
    out[j * 5 + 4] = keep ? conf_s[j] : 0.0f;
}

// concat y_bs[:, :4] + r_bs[:, :4] -> xyxy; col 4 -> conf
__global__ void concat_final(const float* __restrict__ y_bs, const float* __restrict__ r_bs,
                             float* __restrict__ xyxy, float* __restrict__ conf,
                             int Ny, int Nr) {
    int i = blockIdx.x * blockDim.x + threadIdx.x;
    if (i >= Ny + Nr) return;
    const float* src = (i < Ny) ? (y_bs + (size_t)i * 5) : (r_bs + (size_t)(i - Ny) * 5);
    xyxy[i * 4 + 0] = src[0];
    xyxy[i * 4 + 1] = src[1];
    xyxy[i * 4 + 2] = src[2];
    xyxy[i * 4 + 3] = src[3];
    conf[i] = src[4];
}

static void run_nms_stage(const float* xyxy_in, const float* conf_in,
                          float* xyxy_s, float* conf_s,
                          uint64_t* removed, uint64_t* mask,
                          float* out_bs, int N, hipStream_t stream) {
    int nch = (N + 63) / 64;
    sort_by_conf<<<(N + 255) / 256, 256, 0, stream>>>(xyxy_in, conf_in, xyxy_s, conf_s, N);
    nms_mask_row<<<N, 256, 0, stream>>>(xyxy_s, mask, N, nch);
    nms_scan_wave<<<1, 64, 0, stream>>>(conf_s, mask, removed, N, nch);
    write_bs<<<(N + 255) / 256, 256, 0, stream>>>(xyxy_s, conf_s, removed, out_bs, N);
}

extern "C" void kernel_launch(void* const* d_in, const int* in_sizes, int n_in,
                              void* d_out, int out_size, void* d_ws, size_t ws_size,
                              hipStream_t stream) {
    const float* yolo   = (const float*)d_in[0];  // (1,5,8400)
    const float* rtdetr = (const float*)d_in[1];  // (1,300,5)
    float* out = (float*)d_out;                   // (8700,5)
    float* ws  = (float*)d_ws;

    // ws layout (floats)
    float* xyxy_in = ws;                 // 8700*4 = 34800
    float* conf_in = ws + 34800;         // 8700
    float* xyxy_s  = ws + 43500;         // 34800 (16B-aligned)
    float* conf_s  = ws + 78300;         // 8700
    float* y_bs    = ws + 87000;         // 8400*5 = 42000
    float* r_bs    = ws + 129000;        // 300*5  = 1500
    uint64_t* removed = (uint64_t*)((char*)d_ws + 522000);           // 136 u64
    uint64_t* mask    = (uint64_t*)((char*)d_ws + 523088);           // 8700*136 u64 (~9.5MB)

    // Stage 1: YOLO
    prep_yolo<<<(NY + 255) / 256, 256, 0, stream>>>(yolo, xyxy_in, conf_in, NY);
    run_nms_stage(xyxy_in, conf_in, xyxy_s, conf_s, removed, mask, y_bs, NY, stream);

    // Stage 2: RT-DETR
    prep_rtdetr<<<1, 512, 0, stream>>>(rtdetr, xyxy_in, conf_in, NR);
    run_nms_stage(xyxy_in, conf_in, xyxy_s, conf_s, removed, mask, r_bs, NR, stream);

    // Stage 3: final over concat
    concat_final<<<(NF + 255) / 256, 256, 0, stream>>>(y_bs, r_bs, xyxy_in, conf_in, NY, NR);
    run_nms_stage(xyxy_in, conf_in, xyxy_s, conf_s, removed, mask, out, NF, stream);
}

// Round 3
// 1482.537 us; speedup vs baseline: 2.6579x; 1.5095x over previous
//
#include <hip/hip_runtime.h>
#include <cstdint>
#include <cstddef>

#define NY 8400
#define NR 300
#define NF 8700
#define STHR 0.5f
#define ITHR 0.5f
#define NSPLIT 8
#define G 8
#define NPAD 8704

// IOU with explicit-rounding ops so fp-contraction cannot perturb the
// iou > 0.5 comparison vs the numpy fp32 reference.
__device__ __forceinline__ float iou_pair(float4 a, float4 b) {
    float ltx = fmaxf(a.x, b.x);
    float lty = fmaxf(a.y, b.y);
    float rbx = fminf(a.z, b.z);
    float rby = fminf(a.w, b.w);
    float w = fmaxf(__fsub_rn(rbx, ltx), 0.0f);
    float h = fmaxf(__fsub_rn(rby, lty), 0.0f);
    float inter  = __fmul_rn(w, h);
    float area_a = __fmul_rn(__fsub_rn(a.z, a.x), __fsub_rn(a.w, a.y));
    float area_b = __fmul_rn(__fsub_rn(b.z, b.x), __fsub_rn(b.w, b.y));
    float denom  = __fsub_rn(__fadd_rn(area_a, area_b), inter);
    float d = denom > 0.0f ? denom : 1.0f;
    return __fdiv_rn(inter, d);
}

__global__ void prep_yolo(const float* __restrict__ y,
                          float* __restrict__ xyxy, float* __restrict__ conf, int N) {
    int i = blockIdx.x * blockDim.x + threadIdx.x;
    if (i >= N) return;
    float cx = y[0 * N + i], cy = y[1 * N + i];
    float w  = y[2 * N + i], h  = y[3 * N + i];
    float c  = y[4 * N + i];
    xyxy[i * 4 + 0] = cx - w * 0.5f;
    xyxy[i * 4 + 1] = cy - h * 0.5f;
    xyxy[i * 4 + 2] = cx + w * 0.5f;
    xyxy[i * 4 + 3] = cy + h * 0.5f;
    conf[i] = c;
}

__global__ void prep_rtdetr(const float* __restrict__ r,
                            float* __restrict__ xyxy, float* __restrict__ conf, int N) {
    __shared__ float red[512];
    int t = threadIdx.x;
    float m = -INFINITY;
    for (int i = t; i < N; i += blockDim.x) m = fmaxf(m, r[i * 5 + 4]);
    red[t] = m;
    __syncthreads();
    for (int s = 256; s > 0; s >>= 1) {
        if (t < s) red[t] = fmaxf(red[t], red[t + s]);
        __syncthreads();
    }
    float mx = red[0];
    for (int i = t; i < N; i += blockDim.x) {
        float cx = r[i * 5 + 0], cy = r[i * 5 + 1];
        float w  = r[i * 5 + 2], h  = r[i * 5 + 3];
        float c  = r[i * 5 + 4];
        xyxy[i * 4 + 0] = cx - w * 0.5f;
        xyxy[i * 4 + 1] = cy - h * 0.5f;
        xyxy[i * 4 + 2] = cx + w * 0.5f;
        xyxy[i * 4 + 3] = cy + h * 0.5f;
        conf[i] = __fdiv_rn(c, mx);
    }
}

// Partial stable-descending rank over j-slice blockIdx.y. LDS-tiled; all lanes
// read the same LDS word per iter (broadcast, conflict-free). No atomics.
__global__ void rank_partial(const float* __restrict__ conf, int* __restrict__ partial, int N) {
    __shared__ float kk[1152];
    int i  = blockIdx.x * 256 + threadIdx.x;
    int js = blockIdx.y;
    int slice = (N + NSPLIT - 1) / NSPLIT;
    int j0 = js * slice;
    int j1 = min(N, j0 + slice);
    for (int j = j0 + threadIdx.x; j < j1; j += 256) {
        float c = conf[j];
        kk[j - j0] = (c >= STHR) ? c : -1.0f;
    }
    __syncthreads();
    float ci = (i < N) ? conf[i] : 0.0f;
    float ki = (ci >= STHR) ? ci : -1.0f;
    int r = 0;
    int len = j1 - j0;
    for (int jj = 0; jj < len; ++jj) {
        float kj = kk[jj];
        int j = j0 + jj;
        r += (kj > ki) || (kj == ki && j < i);
    }
    if (i < N) partial[js * NPAD + i] = r;
}

// rank = sum of partials; scatter box+conf to sorted position.
__global__ void rank_scatter(const float* __restrict__ xyxy, const float* __restrict__ conf,
                             const int* __restrict__ partial,
                             float* __restrict__ xyxy_s, float* __restrict__ conf_s, int N) {
    int i = blockIdx.x * blockDim.x + threadIdx.x;
    if (i >= N) return;
    int rank = 0;
    #pragma unroll
    for (int js = 0; js < NSPLIT; ++js) rank += partial[js * NPAD + i];
    xyxy_s[rank * 4 + 0] = xyxy[i * 4 + 0];
    xyxy_s[rank * 4 + 1] = xyxy[i * 4 + 1];
    xyxy_s[rank * 4 + 2] = xyxy[i * 4 + 2];
    xyxy_s[rank * 4 + 3] = xyxy[i * 4 + 3];
    conf_s[rank] = conf[i];
}

// One block per row i; 4 waves stride chunks. Below-diagonal chunks are
// ZERO-FILLED so the scan can OR whole rows unmasked.
__global__ void nms_mask_row(const float* __restrict__ xyxy_s, uint64_t* __restrict__ mask,
                             int N, int nch, int stride) {
    int i = blockIdx.x;
    int lane = threadIdx.x & 63;
    int wv   = threadIdx.x >> 6;
    float4 bi = *(const float4*)(xyxy_s + (size_t)i * 4);
    for (int c = wv; c < nch; c += 4) {
        if (c < (i >> 6)) {
            if (lane == 0) mask[(size_t)i * stride + c] = 0ull;
            continue;
        }
        int j = (c << 6) + lane;
        bool bit = false;
        if (j < N && j > i) {
            float4 bj = *(const float4*)(xyxy_s + (size_t)j * 4);
            bit = iou_pair(bi, bj) > ITHR;
        }
        uint64_t m = __ballot(bit);
        if (lane == 0) mask[(size_t)i * stride + c] = m;
    }
}

__device__ __forceinline__ uint64_t shfl64(uint64_t v, int src) {
    int lo = __shfl((int)(uint32_t)v, src, 64);
    int hi = __shfl((int)(uint32_t)(v >> 32), src, 64);
    return ((uint64_t)(uint32_t)hi << 32) | (uint32_t)lo;
}

// Speculative streaming scan: load ALL valid rows in order through a depth-4
// register ring (groups of G=8 rows, compile-time slot indices); resolve
// strictly in order, discarding rows of suppressed candidates. Load stream is
// independent of resolve -> ~3 groups always in flight, latency hidden.
// Bitmap ownership: lane l holds chunks 2l (rem0), 2l+1 (rem1), 128+l (rem2).
__global__ __launch_bounds__(64, 1)
void nms_scan_pipe(const float* __restrict__ conf_s, const uint64_t* __restrict__ mask,
                   uint64_t* __restrict__ removed_out, int N, int nch, int stride) {
    int lane = threadIdx.x;

    int cnt = 0;
    for (int j = lane; j < N; j += 64) cnt += (conf_s[j] >= STHR) ? 1 : 0;
    #pragma unroll
    for (int s = 32; s > 0; s >>= 1) cnt += __shfl_down(cnt, s, 64);
    int nvalid = __shfl(cnt, 0, 64);

    auto initc = [&](int cc) -> uint64_t {
        if (cc >= nch) return ~0ull;
        int base = cc << 6;
        if (base >= nvalid) return ~0ull;
        if (base + 64 > nvalid) return (~0ull) << (nvalid - base);
        return 0ull;
    };
    uint64_t rem0 = initc(2 * lane);
    uint64_t rem1 = initc(2 * lane + 1);
    uint64_t rem2 = initc(128 + lane);

    ulonglong2 sb[4][G];
    uint64_t   st[4][G];
    uint64_t curw = 0;
    int ngroups = (nvalid + G - 1) / G;
    bool tail = (nch > 128);

#define ISSUE(S, GRP) do {                                                   \
    int _g = (GRP);                                                          \
    if (_g < ngroups) {                                                      \
        _Pragma("unroll")                                                    \
        for (int k = 0; k < G; ++k) {                                        \
            int i_ = _g * G + k;                                             \
            ulonglong2 v; v.x = 0ull; v.y = 0ull;                            \
            uint64_t tv = 0ull;                                              \
            if (i_ < nvalid) {                                               \
                const uint64_t* rb = mask + (size_t)i_ * stride;             \
                v = *((const ulonglong2*)rb + lane);                         \
                if (tail && 128 + lane < nch) tv = rb[128 + lane];           \
            }                                                                \
            sb[S][k] = v; st[S][k] = tv;                                     \
        }                                                                    \
    }                                                                        \
} while (0)

#define RESOLVE(S, GRP) do {                                                 \
    int _g = (GRP);                                                          \
    if (_g < ngroups) {                                                      \
        _Pragma("unroll")                                                    \
        for (int k = 0; k < G; ++k) {                                        \
            int i_ = _g * G + k;                                             \
            if (i_ < nvalid) {                                               \
                int c_ = i_ >> 6;                                            \
                if ((i_ & 63) == 0) {                                        \
                    uint64_t rv = (c_ < 128) ? ((c_ & 1) ? rem1 : rem0) : rem2; \
                    curw = shfl64(rv, (c_ < 128) ? (c_ >> 1) : (c_ - 128));  \
                }                                                            \
                uint64_t bit = 1ull << (i_ & 63);                            \
                if (!(curw & bit)) {                                         \
                    ulonglong2 v = sb[S][k]; uint64_t tv = st[S][k];         \
                    rem0 |= v.x; rem1 |= v.y; rem2 |= tv;                    \
                    uint64_t rw = (c_ < 128) ? ((c_ & 1) ? v.y : v.x) : tv;  \
                    curw |= shfl64(rw, (c_ < 128) ? (c_ >> 1) : (c_ - 128)); \
                }                                                            \
            }                                                                \
        }                                                                    \
    }                                                                        \
} while (0)

    ISSUE(0, 0); ISSUE(1, 1); ISSUE(2, 2);
    for (int g0 = 0; g0 < ngroups; g0 += 4) {
        ISSUE(3, g0 + 3); RESOLVE(0, g0);
        ISSUE(0, g0 + 4); RESOLVE(1, g0 + 1);
        ISSUE(1, g0 + 5); RESOLVE(2, g0 + 2);
        ISSUE(2, g0 + 6); RESOLVE(3, g0 + 3);
    }
#undef ISSUE
#undef RESOLVE

    if (2 * lane < nch)     removed_out[2 * lane]     = rem0;
    if (2 * lane + 1 < nch) removed_out[2 * lane + 1] = rem1;
    if (128 + lane < nch)   removed_out[128 + lane]   = rem2;
}

// final stage: out rows [box, conf] stride 5
__global__ void write_bs(const float* __restrict__ xyxy_s, const float* __restrict__ conf_s,
                         const uint64_t* __restrict__ removed,
                         float* __restrict__ out, int N) {
    int j = blockIdx.x * blockDim.x + threadIdx.x;
    if (j >= N) return;
    bool keep = !((removed[j >> 6] >> (j & 63)) & 1ull);
    float4 b = *(const float4*)(xyxy_s + (size_t)j * 4);
    out[j * 5 + 0] = keep ? b.x : 0.0f;
    out[j * 5 + 1] = keep ? b.y : 0.0f;
    out[j * 5 + 2] = keep ? b.z : 0.0f;
    out[j * 5 + 3] = keep ? b.w : 0.0f;
    out[j * 5 + 4] = keep ? conf_s[j] : 0.0f;
}

// stage 1/2: write kept rows straight into stage-3 input arrays (fused concat)
__global__ void write_split(const float* __restrict__ xyxy_s, const float* __restrict__ conf_s,
                            const uint64_t* __restrict__ removed,
                            float* __restrict__ xf, float* __restrict__ cf, int N, int off) {
    int j = blockIdx.x * blockDim.x + threadIdx.x;
    if (j >= N) return;
    bool keep = !((removed[j >> 6] >> (j & 63)) & 1ull);
    float4 b = *(const float4*)(xyxy_s + (size_t)j * 4);
    int o = off + j;
    xf[o * 4 + 0] = keep ? b.x : 0.0f;
    xf[o * 4 + 1] = keep ? b.y : 0.0f;
    xf[o * 4 + 2] = keep ? b.z : 0.0f;
    xf[o * 4 + 3] = keep ? b.w : 0.0f;
    cf[o] = keep ? conf_s[j] : 0.0f;
}

static void run_stage(const float* xyxy_in, const float* conf_in,
                      float* xyxy_s, float* conf_s, int* partial,
                      uint64_t* removed, uint64_t* mask,
                      int N, int stride, hipStream_t stream,
                      float* out5, float* xf, float* cf, int off) {
    int nch = (N + 63) / 64;
    dim3 gA((N + 255) / 256, NSPLIT);
    rank_partial<<<gA, 256, 0, stream>>>(conf_in, partial, N);
    rank_scatter<<<(N + 255) / 256, 256, 0, stream>>>(xyxy_in, conf_in, partial, xyxy_s, conf_s, N);
    nms_mask_row<<<N, 256, 0, stream>>>(xyxy_s, mask, N, nch, stride);
    nms_scan_pipe<<<1, 64, 0, stream>>>(conf_s, mask, removed, N, nch, stride);
    if (out5)
        write_bs<<<(N + 255) / 256, 256, 0, stream>>>(xyxy_s, conf_s, removed, out5, N);
    else
        write_split<<<(N + 255) / 256, 256, 0, stream>>>(xyxy_s, conf_s, removed, xf, cf, N, off);
}

extern "C" void kernel_launch(void* const* d_in, const int* in_sizes, int n_in,
                              void* d_out, int out_size, void* d_ws, size_t ws_size,
                              hipStream_t stream) {
    const float* yolo   = (const float*)d_in[0];  // (1,5,8400)
    const float* rtdetr = (const float*)d_in[1];  // (1,300,5)
    float* out = (float*)d_out;                   // (8700,5)
    float* ws  = (float*)d_ws;

    // ws layout (floats)
    float* xyxy_in = ws;                 // 8700*4
    float* conf_in = ws + 34800;         // 8700
    float* xyxy_s  = ws + 43500;         // 8700*4 (16B aligned)
    float* conf_s  = ws + 78300;         // 8700
    float* xyxy_f  = ws + 87000;         // 8700*4 (stage-3 input, fused concat)
    float* conf_f  = ws + 121800;        // 8700 -> ends 130500 floats = 522000 B
    uint64_t* removed = (uint64_t*)((char*)d_ws + 522000);   // 136 u64
    uint64_t* mask    = (uint64_t*)((char*)d_ws + 523088);   // 8700*136*8 = 9,465,600 B
    int* partial = (int*)mask;           // 8*8704*4 = 278KB, dead before mask is written

    // Stage 1: YOLO (stride = nch = 132, even)
    prep_yolo<<<(NY + 255) / 256, 256, 0, stream>>>(yolo, xyxy_in, conf_in, NY);
    run_stage(xyxy_in, conf_in, xyxy_s, conf_s, partial, removed, mask,
              NY, 132, stream, nullptr, xyxy_f, conf_f, 0);

    // Stage 2: RT-DETR (nch = 5, stride padded to 6 for 16B-aligned rows)
    prep_rtdetr<<<1, 512, 0, stream>>>(rtdetr, xyxy_in, conf_in, NR);
    run_stage(xyxy_in, conf_in, xyxy_s, conf_s, partial, removed, mask,
              NR, 6, stream, nullptr, xyxy_f, conf_f, NY);

    // Stage 3: final over fused concat (stride = nch = 136, even)
    run_stage(xyxy_f, conf_f, xyxy_s, conf_s, partial, removed, mask,
              NF, 136, stream, out, nullptr, nullptr, 0);
}